// Round 1
// baseline (89.732 us; speedup 1.0000x reference)
//
#include <hip/hip_runtime.h>
#include <hip/hip_bf16.h>

#define TD 10          // tree depth
#define NCOL 256       // input dim
#define ROWS_PER_BLOCK 256
#define CHUNK_COLS 32  // columns staged per chunk
#define NCHUNK (NCOL / CHUNK_COLS)   // 8

// ---- async global->LDS (16B per lane), dest is wave-uniform base + lane*16 ----
typedef const __attribute__((address_space(1))) void* as1_cvp;
typedef __attribute__((address_space(3))) void* as3_vp;

__device__ __forceinline__ void gload_lds16(const float* g, float* l) {
  __builtin_amdgcn_global_load_lds((as1_cvp)(const void*)g, (as3_vp)(void*)l, 16, 0, 0);
}

// ---- fully-unrolled DFS fold over the leaf tree ----
// LEVEL 0 = MSB (d=0).  left child = bit 0 -> q[d],  right child = bit 1 -> p[d].
template <int LEVEL, int IDX>
__device__ __forceinline__ void fold(const float* __restrict__ lv,
                                     const float (&p)[TD], const float (&q)[TD],
                                     float prefix, float& acc) {
  if constexpr (LEVEL == TD - 1) {
    const float l0 = lv[2 * IDX];
    const float l1 = lv[2 * IDX + 1];
    // t = q9*l0 + p9*l1 ; acc += prefix*t
    acc = fmaf(prefix, fmaf(p[TD - 1], l1, q[TD - 1] * l0), acc);
  } else {
    fold<LEVEL + 1, 2 * IDX>(lv, p, q, prefix * q[LEVEL], acc);
    fold<LEVEL + 1, 2 * IDX + 1>(lv, p, q, prefix * p[LEVEL], acc);
  }
}

__global__ void __launch_bounds__(256, 2)
odt_kernel(const float* __restrict__ x, const float* __restrict__ W,
           const float* __restrict__ bias, const float* __restrict__ lv,
           float* __restrict__ out) {
  // per-wave private double-buffered staging: [wave][buf][64 rows * 32 cols]
  __shared__ float xs[4][2][64 * CHUNK_COLS];

  const int lane = threadIdx.x & 63;
  const int wave = threadIdx.x >> 6;
  const int row0 = blockIdx.x * ROWS_PER_BLOCK + wave * 64;  // wave's first row
  const float* __restrict__ xw = x + (size_t)row0 * NCOL;

  // Stage chunk -> xs[wave][buf].  LDS fill is linear (instr i, lane l ->
  // words i*256 + l*4..+3).  We pre-swizzle the GLOBAL source so the stored
  // layout is: word(r, c) = r*32 + ((c>>2 ^ (r&7))<<2 | (c&3)).
  auto stage = [&](int chunk, int buf) {
    const float* src0 = xw + chunk * CHUNK_COLS;
#pragma unroll
    for (int i = 0; i < 8; ++i) {
      const int r = i * 8 + (lane >> 3);
      const int c = ((lane & 7) ^ (r & 7)) << 2;
      const float* src = src0 + (size_t)r * NCOL + c;
      float* dst = &xs[wave][buf][i * 256];  // wave-uniform
      gload_lds16(src, dst);
    }
  };

  float sums[TD];
#pragma unroll
  for (int d = 0; d < TD; ++d) sums[d] = bias[d];  // uniform -> s_load

  stage(0, 0);

  for (int chunk = 0; chunk < NCHUNK; ++chunk) {
    const int buf = chunk & 1;
    if (chunk < NCHUNK - 1) {
      stage(chunk + 1, buf ^ 1);
      asm volatile("s_waitcnt vmcnt(8)" ::: "memory");  // current buf's 8 loads done
    } else {
      asm volatile("s_waitcnt vmcnt(0)" ::: "memory");
    }
#pragma unroll
    for (int c4 = 0; c4 < CHUNK_COLS / 4; ++c4) {
      const float4 xv = *(const float4*)&xs[wave][buf][lane * CHUNK_COLS +
                                                       ((c4 ^ (lane & 7)) << 2)];
#pragma unroll
      for (int e = 0; e < 4; ++e) {
        const float xe = (&xv.x)[e];
        const int col = chunk * CHUNK_COLS + c4 * 4 + e;  // uniform
#pragma unroll
        for (int d = 0; d < TD; ++d)
          sums[d] = fmaf(xe, W[col * TD + d], sums[d]);  // W uniform -> s_load
      }
    }
  }

  // sigmoid
  float p[TD], q[TD];
#pragma unroll
  for (int d = 0; d < TD; ++d) {
    const float s = 1.0f / (1.0f + __expf(-sums[d]));
    p[d] = s;
    q[d] = 1.0f - s;
  }

  // weighted-leaf contraction via DFS (2558 VALU ops, products stay in [0,1])
  float acc = 0.0f;
  fold<0, 0>(lv, p, q, 1.0f, acc);

  out[row0 + lane] = acc;
}

extern "C" void kernel_launch(void* const* d_in, const int* in_sizes, int n_in,
                              void* d_out, int out_size, void* d_ws, size_t ws_size,
                              hipStream_t stream) {
  const float* x = (const float*)d_in[0];
  const float* W = (const float*)d_in[1];
  const float* b = (const float*)d_in[2];
  const float* lv = (const float*)d_in[3];
  float* out = (float*)d_out;

  const int batch = in_sizes[0] / NCOL;          // 262144
  const int grid = batch / ROWS_PER_BLOCK;       // 1024
  odt_kernel<<<grid, 256, 0, stream>>>(x, W, b, lv, out);
}

// Round 2
// 66.531 us; speedup vs baseline: 1.3487x; 1.3487x over previous
//
#include <hip/hip_runtime.h>
#include <hip/hip_bf16.h>

#define TD 10          // tree depth
#define NCOL 256       // input dim
#define ROWS_PER_BLOCK 256
#define CHUNK_COLS 16  // columns staged per chunk
#define NCHUNK (NCOL / CHUNK_COLS)   // 16

// ---- async global->LDS (16B per lane), dest is wave-uniform base + lane*16 ----
typedef const __attribute__((address_space(1))) void* as1_cvp;
typedef __attribute__((address_space(3))) void* as3_vp;

__device__ __forceinline__ void gload_lds16(const float* g, float* l) {
  __builtin_amdgcn_global_load_lds((as1_cvp)(const void*)g, (as3_vp)(void*)l, 16, 0, 0);
}

// ---- DFS fold over the leaf tree, terminated at level TD-3 (8-leaf groups) ----
// LEVEL 0 = MSB (d=0). bit 0 -> q[d], bit 1 -> p[d].
// g[o] = t7*t8*t9 with o = (bit7<<2)|(bit8<<1)|bit9, precomputed once.
template <int LEVEL, int IDX>
__device__ __forceinline__ void fold(const float* __restrict__ lv,
                                     const float (&p)[TD], const float (&q)[TD],
                                     const float (&g)[8],
                                     float prefix, float& acc) {
  if constexpr (LEVEL == TD - 3) {
    const float* l8 = lv + 8 * IDX;          // leaves visited sequentially
    float t = l8[0] * g[0];
    t = fmaf(l8[1], g[1], t);
    t = fmaf(l8[2], g[2], t);
    t = fmaf(l8[3], g[3], t);
    t = fmaf(l8[4], g[4], t);
    t = fmaf(l8[5], g[5], t);
    t = fmaf(l8[6], g[6], t);
    t = fmaf(l8[7], g[7], t);
    acc = fmaf(prefix, t, acc);
  } else {
    fold<LEVEL + 1, 2 * IDX>(lv, p, q, g, prefix * q[LEVEL], acc);
    fold<LEVEL + 1, 2 * IDX + 1>(lv, p, q, g, prefix * p[LEVEL], acc);
  }
}

__global__ void __launch_bounds__(256, 4)
odt_kernel(const float* __restrict__ x, const float* __restrict__ W,
           const float* __restrict__ bias, const float* __restrict__ lv,
           float* __restrict__ out) {
  // per-wave private double-buffered staging: [wave][buf][64 rows * 16 cols]
  // 32 KiB/block -> 4 blocks/CU (VGPR=128 caps waves at 4/SIMD anyway)
  __shared__ float xs[4][2][64 * CHUNK_COLS];

  const int lane = threadIdx.x & 63;
  const int wave = threadIdx.x >> 6;
  const int row0 = blockIdx.x * ROWS_PER_BLOCK + wave * 64;  // wave's first row
  const float* __restrict__ xw = x + (size_t)row0 * NCOL;

  // LDS fill is linear (instr i, lane l -> words i*256 + l*4..+3).
  // Pre-swizzle the GLOBAL source so stored layout is:
  //   word(r, j*4..) = row r, cols ((j ^ (r&3))<<2 ..+3),  j = lane&3
  auto stage = [&](int chunk, int buf) {
    const float* src0 = xw + chunk * CHUNK_COLS;
#pragma unroll
    for (int i = 0; i < 4; ++i) {
      const int r = i * 16 + (lane >> 2);
      const int c = ((lane & 3) ^ (r & 3)) << 2;
      gload_lds16(src0 + (size_t)r * NCOL + c, &xs[wave][buf][i * 256]);
    }
  };

  float sums[TD];
#pragma unroll
  for (int d = 0; d < TD; ++d) sums[d] = bias[d];  // uniform -> s_load

  stage(0, 0);

  for (int chunk = 0; chunk < NCHUNK; ++chunk) {
    const int buf = chunk & 1;
    if (chunk < NCHUNK - 1) {
      stage(chunk + 1, buf ^ 1);
      asm volatile("s_waitcnt vmcnt(4)" ::: "memory");  // current buf's 4 loads done
    } else {
      asm volatile("s_waitcnt vmcnt(0)" ::: "memory");
    }
#pragma unroll
    for (int c4 = 0; c4 < CHUNK_COLS / 4; ++c4) {
      const float4 xv = *(const float4*)&xs[wave][buf][lane * CHUNK_COLS +
                                                       ((c4 ^ (lane & 3)) << 2)];
#pragma unroll
      for (int e = 0; e < 4; ++e) {
        const float xe = (&xv.x)[e];
        const int col = chunk * CHUNK_COLS + c4 * 4 + e;  // uniform
#pragma unroll
        for (int d = 0; d < TD; ++d)
          sums[d] = fmaf(xe, W[col * TD + d], sums[d]);  // W uniform -> s_load
      }
    }
  }

  // sigmoid
  float p[TD], q[TD];
#pragma unroll
  for (int d = 0; d < TD; ++d) {
    const float s = 1.0f / (1.0f + __expf(-sums[d]));
    p[d] = s;
    q[d] = 1.0f - s;
  }

  // precompute last-3-level products: g[o] = t7[o>>2] * t8[(o>>1)&1] * t9[o&1]
  float g[8];
  {
    const float h00 = q[8] * q[9], h01 = q[8] * p[9];
    const float h10 = p[8] * q[9], h11 = p[8] * p[9];
    g[0] = q[7] * h00; g[1] = q[7] * h01; g[2] = q[7] * h10; g[3] = q[7] * h11;
    g[4] = p[7] * h00; g[5] = p[7] * h01; g[6] = p[7] * h10; g[7] = p[7] * h11;
  }

  // weighted-leaf contraction: DFS over levels 0..6 (127 nodes, 254 muls),
  // then 128 x 8-leaf groups (9 ops each) => ~1430 VALU ops total
  float acc = 0.0f;
  fold<0, 0>(lv, p, q, g, 1.0f, acc);

  out[row0 + lane] = acc;
}

extern "C" void kernel_launch(void* const* d_in, const int* in_sizes, int n_in,
                              void* d_out, int out_size, void* d_ws, size_t ws_size,
                              hipStream_t stream) {
  const float* x = (const float*)d_in[0];
  const float* W = (const float*)d_in[1];
  const float* b = (const float*)d_in[2];
  const float* lv = (const float*)d_in[3];
  float* out = (float*)d_out;

  const int batch = in_sizes[0] / NCOL;          // 262144
  const int grid = batch / ROWS_PER_BLOCK;       // 1024
  odt_kernel<<<grid, 256, 0, stream>>>(x, W, b, lv, out);
}